// Round 5
// baseline (640.279 us; speedup 1.0000x reference)
//
#include <hip/hip_runtime.h>
#include <hip/hip_bf16.h>
#include <cstdint>

#define B_SZ   512
#define NLAT   64
#define H_SZ   32
#define G_OI_N 5000
#define K_SZ   64

// ---------------- Kernel A: h = BN(relu(latent @ W1 + b1)) -> fp32 [512][32]
// Reference layout: W1 is (N_LATENT=64, H=32) C-order: W1[l*32 + j].
__global__ __launch_bounds__(256) void mlp_kernel(
    const float* __restrict__ latent, const float* __restrict__ W1,
    const float* __restrict__ b1, const float* __restrict__ gamma,
    const float* __restrict__ beta, const float* __restrict__ mean,
    const float* __restrict__ var, float* __restrict__ hout)
{
    int idx = blockIdx.x * 256 + threadIdx.x;   // 0..16383 = b*32 + j
    int b = idx >> 5;
    int j = idx & 31;
    float acc = 0.f;
    const float4* lp = reinterpret_cast<const float4*>(latent + b * NLAT);
#pragma unroll
    for (int q = 0; q < NLAT / 4; ++q) {
        float4 lv = lp[q];
        acc = fmaf(lv.x, W1[(4 * q + 0) * H_SZ + j], acc);
        acc = fmaf(lv.y, W1[(4 * q + 1) * H_SZ + j], acc);
        acc = fmaf(lv.z, W1[(4 * q + 2) * H_SZ + j], acc);
        acc = fmaf(lv.w, W1[(4 * q + 3) * H_SZ + j], acc);
    }
    acc += b1[j];
    acc = fmaxf(acc, 0.f);
    acc = gamma[j] * (acc - mean[j]) * rsqrtf(var[j] + 1e-5f) + beta[j];
    hout[idx] = acc;
}

// ---------------- Kernel B: logit[b,g,k] = sum_h h[b,h] * lw[genes[g],h,k]
// One block per gene, 4 waves x 128 b-rows, lane = k. FP32 stores (coalesced 256B/wave).
__global__ __launch_bounds__(256) void logit_kernel(
    const float* __restrict__ hbuf, const int* __restrict__ genes,
    const float* __restrict__ lw, float* __restrict__ out)
{
    const int g = blockIdx.x;
    const int lane = threadIdx.x & 63;
    const int w = threadIdx.x >> 6;
    const size_t gene = (size_t)genes[g];

    const float* wp = lw + gene * (size_t)(H_SZ * K_SZ) + lane;
    float wreg[H_SZ];
#pragma unroll
    for (int hh = 0; hh < H_SZ; ++hh) wreg[hh] = wp[hh * K_SZ];

    float* outp = out + (size_t)g * K_SZ + lane;
    const int b0 = w * 128;
    for (int b = b0; b < b0 + 128; ++b) {
        const float4* hp = reinterpret_cast<const float4*>(hbuf + b * H_SZ);
        float a0 = 0.f, a1 = 0.f, a2 = 0.f, a3 = 0.f;
#pragma unroll
        for (int q = 0; q < 8; ++q) {
            float4 hv = hp[q];
            a0 = fmaf(hv.x, wreg[4 * q + 0], a0);
            a1 = fmaf(hv.y, wreg[4 * q + 1], a1);
            a2 = fmaf(hv.z, wreg[4 * q + 2], a2);
            a3 = fmaf(hv.w, wreg[4 * q + 3], a3);
        }
        outp[(size_t)b * (G_OI_N * K_SZ)] = (a0 + a1) + (a2 + a3);
    }
}

// ---------------- Kernel C: rho[b,g] = sum_h h[b,h] * rw[genes[g],h]
__global__ __launch_bounds__(256) void rho_kernel(
    const float* __restrict__ hbuf, const int* __restrict__ genes,
    const float* __restrict__ rw, float* __restrict__ out)
{
    const int gx = blockIdx.x % 20;
    const int bx = blockIdx.x / 20;
    const int g = gx * 256 + threadIdx.x;
    if (g >= G_OI_N) return;
    const size_t gene = (size_t)genes[g];

    float rreg[H_SZ];
    const float4* rp = reinterpret_cast<const float4*>(rw + gene * H_SZ);
#pragma unroll
    for (int q = 0; q < 8; ++q) {
        float4 rv = rp[q];
        rreg[4 * q + 0] = rv.x; rreg[4 * q + 1] = rv.y;
        rreg[4 * q + 2] = rv.z; rreg[4 * q + 3] = rv.w;
    }

    const int b0 = bx * 32;
    for (int b = b0; b < b0 + 32; ++b) {
        const float4* hp = reinterpret_cast<const float4*>(hbuf + b * H_SZ);
        float a0 = 0.f, a1 = 0.f, a2 = 0.f, a3 = 0.f;
#pragma unroll
        for (int q = 0; q < 8; ++q) {
            float4 hv = hp[q];
            a0 = fmaf(hv.x, rreg[4 * q + 0], a0);
            a1 = fmaf(hv.y, rreg[4 * q + 1], a1);
            a2 = fmaf(hv.z, rreg[4 * q + 2], a2);
            a3 = fmaf(hv.w, rreg[4 * q + 3], a3);
        }
        out[(size_t)b * G_OI_N + g] = (a0 + a1) + (a2 + a3);
    }
}

extern "C" void kernel_launch(void* const* d_in, const int* in_sizes, int n_in,
                              void* d_out, int out_size, void* d_ws, size_t ws_size,
                              hipStream_t stream)
{
    // Bind inputs by SIZE SIGNATURE (all sizes unique; robust to ordering).
    const float *latent = nullptr, *W1 = nullptr, *lw = nullptr, *rw = nullptr;
    const int* genes = nullptr;
    const float* small[5] = {nullptr, nullptr, nullptr, nullptr, nullptr};
    int nsmall = 0;
    for (int i = 0; i < n_in; ++i) {
        switch (in_sizes[i]) {
            case 32768:    latent = (const float*)d_in[i]; break;
            case 5000:
            case 10000:    genes  = (const int*)d_in[i];   break;
            case 2048:     W1     = (const float*)d_in[i]; break;
            case 40960000: lw     = (const float*)d_in[i]; break;
            case 640000:   rw     = (const float*)d_in[i]; break;
            case 32: if (nsmall < 5) small[nsmall++] = (const float*)d_in[i]; break;
            default: break;
        }
    }
    if (!latent || !genes || !W1 || !lw || !rw || nsmall < 5) return;
    const float* b1v   = small[0];
    const float* gamma = small[1];
    const float* beta  = small[2];
    const float* mean  = small[3];
    const float* var   = small[4];

    float* hbuf = (float*)d_ws;                               // 64 KB scratch
    float* logit_out = (float*)d_out;                         // [512,5000,64] fp32
    float* rho_out   = logit_out + (size_t)B_SZ * G_OI_N * K_SZ;  // [512,5000] fp32

    mlp_kernel<<<(B_SZ * H_SZ) / 256, 256, 0, stream>>>(latent, W1, b1v, gamma, beta,
                                                        mean, var, hbuf);
    logit_kernel<<<G_OI_N, 256, 0, stream>>>(hbuf, genes, lw, logit_out);
    rho_kernel<<<20 * 16, 256, 0, stream>>>(hbuf, genes, rw, rho_out);
}

// Round 6
// 202.350 us; speedup vs baseline: 3.1642x; 3.1642x over previous
//
#include <hip/hip_runtime.h>
#include <hip/hip_bf16.h>
#include <cstdint>

#define B_SZ   512
#define NLAT   64
#define H_SZ   32
#define G_OI_N 5000
#define K_SZ   64

// ---------------- Kernel A: h = BN(relu(latent @ W1 + b1)) -> fp32 [512][32]
__global__ __launch_bounds__(256) void mlp_kernel(
    const float* __restrict__ latent, const float* __restrict__ W1,
    const float* __restrict__ b1, const float* __restrict__ gamma,
    const float* __restrict__ beta, const float* __restrict__ mean,
    const float* __restrict__ var, float* __restrict__ hout)
{
    int idx = blockIdx.x * 256 + threadIdx.x;   // 0..16383 = b*32 + j
    int b = idx >> 5;
    int j = idx & 31;
    float acc = 0.f;
    const float4* lp = reinterpret_cast<const float4*>(latent + b * NLAT);
#pragma unroll
    for (int q = 0; q < NLAT / 4; ++q) {
        float4 lv = lp[q];
        acc = fmaf(lv.x, W1[(4 * q + 0) * H_SZ + j], acc);
        acc = fmaf(lv.y, W1[(4 * q + 1) * H_SZ + j], acc);
        acc = fmaf(lv.z, W1[(4 * q + 2) * H_SZ + j], acc);
        acc = fmaf(lv.w, W1[(4 * q + 3) * H_SZ + j], acc);
    }
    acc += b1[j];
    acc = fmaxf(acc, 0.f);
    acc = gamma[j] * (acc - mean[j]) * rsqrtf(var[j] + 1e-5f) + beta[j];
    hout[idx] = acc;
}

// ---------------- Kernel B: logit[b,g,k] = sum_h h[b,h] * lw[genes[g],h,k]
// Block = 4 genes (one per wave) x shared 128-row b-slice.
// The 4 waves read the SAME 16KB h-slice -> L1-resident (fixes the L2-latency
// serialization measured in round 5: VALUBusy 31%, 640 cyc/iter exposed).
// lane = k -> coalesced 256B/wave fp32 stores, wreg (lw column) in registers.
__global__ __launch_bounds__(256) void logit_kernel(
    const float* __restrict__ hbuf, const int* __restrict__ genes,
    const float* __restrict__ lw, float* __restrict__ out)
{
    const int slice = blockIdx.x & 3;          // b-slice: 128 rows
    const int gq    = blockIdx.x >> 2;         // gene quad: 0..1249
    const int lane  = threadIdx.x & 63;        // k
    const int w     = threadIdx.x >> 6;        // wave -> gene within quad
    const int g     = gq * 4 + w;              // < 5000 always (1250*4)
    const size_t gene = (size_t)genes[g];

    const float* wp = lw + gene * (size_t)(H_SZ * K_SZ) + lane;
    float wreg[H_SZ];
#pragma unroll
    for (int hh = 0; hh < H_SZ; ++hh) wreg[hh] = wp[hh * K_SZ];

    float* outp = out + (size_t)g * K_SZ + lane;
    const int b0 = slice * 128;
#pragma unroll 2
    for (int bb = 0; bb < 128; ++bb) {
        const int b = b0 + bb;
        const float4* hp = reinterpret_cast<const float4*>(hbuf + b * H_SZ);
        float a0 = 0.f, a1 = 0.f, a2 = 0.f, a3 = 0.f;
#pragma unroll
        for (int q = 0; q < 8; ++q) {
            float4 hv = hp[q];
            a0 = fmaf(hv.x, wreg[4 * q + 0], a0);
            a1 = fmaf(hv.y, wreg[4 * q + 1], a1);
            a2 = fmaf(hv.z, wreg[4 * q + 2], a2);
            a3 = fmaf(hv.w, wreg[4 * q + 3], a3);
        }
        outp[(size_t)b * (G_OI_N * K_SZ)] = (a0 + a1) + (a2 + a3);
    }
}

// ---------------- Kernel C: rho[b,g] = sum_h h[b,h] * rw[genes[g],h]
__global__ __launch_bounds__(256) void rho_kernel(
    const float* __restrict__ hbuf, const int* __restrict__ genes,
    const float* __restrict__ rw, float* __restrict__ out)
{
    const int gx = blockIdx.x % 20;
    const int bx = blockIdx.x / 20;
    const int g = gx * 256 + threadIdx.x;
    if (g >= G_OI_N) return;
    const size_t gene = (size_t)genes[g];

    float rreg[H_SZ];
    const float4* rp = reinterpret_cast<const float4*>(rw + gene * H_SZ);
#pragma unroll
    for (int q = 0; q < 8; ++q) {
        float4 rv = rp[q];
        rreg[4 * q + 0] = rv.x; rreg[4 * q + 1] = rv.y;
        rreg[4 * q + 2] = rv.z; rreg[4 * q + 3] = rv.w;
    }

    const int b0 = bx * 32;
    for (int b = b0; b < b0 + 32; ++b) {
        const float4* hp = reinterpret_cast<const float4*>(hbuf + b * H_SZ);
        float a0 = 0.f, a1 = 0.f, a2 = 0.f, a3 = 0.f;
#pragma unroll
        for (int q = 0; q < 8; ++q) {
            float4 hv = hp[q];
            a0 = fmaf(hv.x, rreg[4 * q + 0], a0);
            a1 = fmaf(hv.y, rreg[4 * q + 1], a1);
            a2 = fmaf(hv.z, rreg[4 * q + 2], a2);
            a3 = fmaf(hv.w, rreg[4 * q + 3], a3);
        }
        out[(size_t)b * G_OI_N + g] = (a0 + a1) + (a2 + a3);
    }
}

extern "C" void kernel_launch(void* const* d_in, const int* in_sizes, int n_in,
                              void* d_out, int out_size, void* d_ws, size_t ws_size,
                              hipStream_t stream)
{
    // Bind inputs by SIZE SIGNATURE (all sizes unique; robust to ordering).
    const float *latent = nullptr, *W1 = nullptr, *lw = nullptr, *rw = nullptr;
    const int* genes = nullptr;
    const float* small[5] = {nullptr, nullptr, nullptr, nullptr, nullptr};
    int nsmall = 0;
    for (int i = 0; i < n_in; ++i) {
        switch (in_sizes[i]) {
            case 32768:    latent = (const float*)d_in[i]; break;
            case 5000:
            case 10000:    genes  = (const int*)d_in[i];   break;
            case 2048:     W1     = (const float*)d_in[i]; break;
            case 40960000: lw     = (const float*)d_in[i]; break;
            case 640000:   rw     = (const float*)d_in[i]; break;
            case 32: if (nsmall < 5) small[nsmall++] = (const float*)d_in[i]; break;
            default: break;
        }
    }
    if (!latent || !genes || !W1 || !lw || !rw || nsmall < 5) return;
    const float* b1v   = small[0];
    const float* gamma = small[1];
    const float* beta  = small[2];
    const float* mean  = small[3];
    const float* var   = small[4];

    float* hbuf = (float*)d_ws;                               // 64 KB scratch
    float* logit_out = (float*)d_out;                         // [512,5000,64] fp32
    float* rho_out   = logit_out + (size_t)B_SZ * G_OI_N * K_SZ;  // [512,5000] fp32

    mlp_kernel<<<(B_SZ * H_SZ) / 256, 256, 0, stream>>>(latent, W1, b1v, gamma, beta,
                                                        mean, var, hbuf);
    logit_kernel<<<G_OI_N, 256, 0, stream>>>(hbuf, genes, lw, logit_out);
    rho_kernel<<<20 * 16, 256, 0, stream>>>(hbuf, genes, rw, rho_out);
}